// Round 1
// baseline (9088.611 us; speedup 1.0000x reference)
//
#include <hip/hip_runtime.h>
#include <hip/hip_bf16.h>

typedef __attribute__((ext_vector_type(8))) __bf16 bf16x8;
typedef __attribute__((ext_vector_type(4))) float  floatx4;

#define T_STEPS 256
#define BATCH   128
#define HID     512

__device__ __forceinline__ float sigmoidf_(float x) { return 1.f / (1.f + __expf(-x)); }
__device__ __forceinline__ float tanhf_(float y) {
  float e = __expf(-2.f * fabsf(y));
  return copysignf((1.f - e) / (1.f + e), y);
}

// fp32 -> bf16 elementwise (x conversion), 8 elems/thread
__global__ __launch_bounds__(256) void cvt_bf16(const float* __restrict__ in,
                                                __bf16* __restrict__ out, int n8) {
  int i = blockIdx.x * 256 + threadIdx.x;
  if (i >= n8) return;
  const floatx4* p = (const floatx4*)(in + (size_t)i * 8);
  floatx4 a = p[0], b = p[1];
  bf16x8 o;
  o[0] = (__bf16)a[0]; o[1] = (__bf16)a[1]; o[2] = (__bf16)a[2]; o[3] = (__bf16)a[3];
  o[4] = (__bf16)b[0]; o[5] = (__bf16)b[1]; o[6] = (__bf16)b[2]; o[7] = (__bf16)b[3];
  *(bf16x8*)(out + (size_t)i * 8) = o;
}

// Persistent GRU layer scan. 64 blocks; block g owns hidden cols [8g, 8g+8).
// W slice (gates r,z,n for those cols, over K = Kin + 512) lives in LDS in
// MFMA-frag order. Per-step inter-block barrier via flag array; sync latency
// hidden by computing next step's x-phase between post and poll.
__global__ __launch_bounds__(256) void gru_scan(
    const __bf16* __restrict__ xsrc, int sb, int st, int Kin,
    const float* __restrict__ Wih, const float* __restrict__ Whh,
    const float* __restrict__ bih, const float* __restrict__ bhh,
    __bf16* __restrict__ hbuf,   // ping-pong [2][128][512], zero-initialized
    __bf16* __restrict__ hseq,   // [128][256][512] or nullptr
    int* flags)                  // [64], zero-initialized
{
  const int tid = threadIdx.x;
  const int g   = blockIdx.x;     // 0..63
  const int w   = tid >> 6;       // wave 0..3
  const int l   = tid & 63;
  const int c   = l & 15;
  const int q   = l >> 4;
  const int KTx = Kin >> 5;       // x-phase k-tiles (8 or 16)
  const int KT  = KTx + 16;       // + h-phase k-tiles

  __shared__ __bf16 ldsW[2 * 32 * 64 * 8];   // 64 KiB max (KT<=32)

  // ---- stage W slice (fp32 -> bf16) into frag-order LDS
  // tile0 rows: [r0..7 | z0..7], tile1 rows: [n0..7 | zeros]
  for (int cid = tid; cid < 2 * KT * 64; cid += 256) {
    int nt = cid / (KT * 64);
    int r1 = cid - nt * (KT * 64);
    int kt = r1 >> 6;
    int ll = r1 & 63;
    int cc = ll & 15, qq = ll >> 4;
    int k  = kt * 32 + qq * 8;
    int grow;
    if (nt == 0) grow = (cc < 8) ? (g * 8 + cc) : (512 + g * 8 + (cc - 8));
    else         grow = (cc < 8) ? (1024 + g * 8 + cc) : -1;
    bf16x8 v;
    if (grow >= 0) {
      const float* src = (k < Kin) ? (Wih + (size_t)grow * Kin + k)
                                   : (Whh + (size_t)grow * HID + (k - Kin));
      #pragma unroll
      for (int j = 0; j < 8; ++j) v[j] = (__bf16)src[j];
    } else {
      #pragma unroll
      for (int j = 0; j < 8; ++j) v[j] = (__bf16)0.f;
    }
    *(bf16x8*)&ldsW[((size_t)(nt * KT + kt) * 64 + ll) * 8] = v;
  }
  __syncthreads();

  // ---- per-lane biases (constant over steps)
  float bias0, bias_nx, bias_nh;
  if (c < 8) {
    int j = g * 8 + c;
    bias0   = bih[j] + bhh[j];          // r-gate
    bias_nx = bih[1024 + j];
    bias_nh = bhh[1024 + j];
  } else {
    int j2 = g * 8 + (c - 8);
    bias0   = bih[512 + j2] + bhh[512 + j2];  // z-gate (consumed via shfl)
    bias_nx = 0.f; bias_nh = 0.f;
  }

  floatx4 accA[2][2], accB[2][2];
  const floatx4 zero4 = {0.f, 0.f, 0.f, 0.f};

  auto phaseX = [&](int t) {
    accA[0][0] = zero4; accA[0][1] = zero4; accA[1][0] = zero4; accA[1][1] = zero4;
    for (int kt = 0; kt < KTx; ++kt) {
      bf16x8 b0 = *(const bf16x8*)&ldsW[((size_t)(0 * KT + kt) * 64 + l) * 8];
      bf16x8 b1 = *(const bf16x8*)&ldsW[((size_t)(1 * KT + kt) * 64 + l) * 8];
      int k = kt * 32 + q * 8;
      #pragma unroll
      for (int mt = 0; mt < 2; ++mt) {
        int row = (w * 2 + mt) * 16 + c;
        bf16x8 a = *(const bf16x8*)(xsrc + (size_t)row * sb + (size_t)t * st + k);
        accA[mt][0] = __builtin_amdgcn_mfma_f32_16x16x32_bf16(a, b0, accA[mt][0], 0, 0, 0);
        accA[mt][1] = __builtin_amdgcn_mfma_f32_16x16x32_bf16(a, b1, accA[mt][1], 0, 0, 0);
      }
    }
  };

  phaseX(0);

  for (int t = 0; t < T_STEPS; ++t) {
    const __bf16* hR = hbuf + (size_t)(t & 1) * BATCH * HID;
    __bf16*       hW = hbuf + (size_t)((t + 1) & 1) * BATCH * HID;

    // ---- phase H: accB = h_{t-1} @ Whh_slice^T
    accB[0][0] = zero4; accB[0][1] = zero4; accB[1][0] = zero4; accB[1][1] = zero4;
    for (int kt = 0; kt < 16; ++kt) {
      bf16x8 b0 = *(const bf16x8*)&ldsW[((size_t)(0 * KT + KTx + kt) * 64 + l) * 8];
      bf16x8 b1 = *(const bf16x8*)&ldsW[((size_t)(1 * KT + KTx + kt) * 64 + l) * 8];
      int k = kt * 32 + q * 8;
      #pragma unroll
      for (int mt = 0; mt < 2; ++mt) {
        int row = (w * 2 + mt) * 16 + c;
        bf16x8 a = *(const bf16x8*)(hR + (size_t)row * HID + k);
        accB[mt][0] = __builtin_amdgcn_mfma_f32_16x16x32_bf16(a, b0, accB[mt][0], 0, 0, 0);
        accB[mt][1] = __builtin_amdgcn_mfma_f32_16x16x32_bf16(a, b1, accB[mt][1], 0, 0, 0);
      }
    }

    // ---- epilogue: gates + h update (lanes c<8 own one hidden col each)
    #pragma unroll
    for (int mt = 0; mt < 2; ++mt) {
      #pragma unroll
      for (int rg = 0; rg < 4; ++rg) {
        float pre0 = accA[mt][0][rg] + accB[mt][0][rg] + bias0;
        float zs = __shfl(pre0, (l & 48) | ((c + 8) & 15), 64);  // z from lane c+8
        if (c < 8) {
          int row = (w * 2 + mt) * 16 + q * 4 + rg;
          int j = g * 8 + c;
          float r  = sigmoidf_(pre0);
          float z  = sigmoidf_(zs);
          float nn = tanhf_(accA[mt][1][rg] + bias_nx + r * (accB[mt][1][rg] + bias_nh));
          float hp = (float)hR[(size_t)row * HID + j];
          float hnew = (1.f - z) * nn + z * hp;
          __bf16 hb = (__bf16)hnew;
          hW[(size_t)row * HID + j] = hb;
          if (hseq) hseq[((size_t)row * T_STEPS + t) * HID + j] = hb;
        }
      }
    }

    if (t + 1 < T_STEPS) {
      __threadfence();          // agent-scope release of h stores
      __syncthreads();
      if (tid == 0)
        __hip_atomic_store(&flags[g], t + 1, __ATOMIC_RELEASE, __HIP_MEMORY_SCOPE_AGENT);
      phaseX(t + 1);            // no h dependency -> hides barrier latency
      int target = t + 1;
      while (1) {
        int v = __hip_atomic_load(&flags[l], __ATOMIC_ACQUIRE, __HIP_MEMORY_SCOPE_AGENT);
        if (__all(v >= target)) break;
        __builtin_amdgcn_s_sleep(1);
      }
    }
  }
}

// yhat[b][o] = h1_last[b][:] . Wout[o][:] + bout[o]
__global__ __launch_bounds__(64) void outproj(const __bf16* __restrict__ h1,
                                              const float* __restrict__ Wout,
                                              const float* __restrict__ bout,
                                              float* __restrict__ out) {
  int b = blockIdx.x, o = threadIdx.x;
  const __bf16* hr = h1 + (size_t)b * HID;
  const float*  wr = Wout + (size_t)o * HID;
  float acc = bout[o];
  for (int k = 0; k < HID; ++k) acc += (float)hr[k] * wr[k];
  out[b * 64 + o] = acc;
}

extern "C" void kernel_launch(void* const* d_in, const int* in_sizes, int n_in,
                              void* d_out, int out_size, void* d_ws, size_t ws_size,
                              hipStream_t stream) {
  const float* x    = (const float*)d_in[0];
  const float* Wih0 = (const float*)d_in[1];
  const float* Whh0 = (const float*)d_in[2];
  const float* bih0 = (const float*)d_in[3];
  const float* bhh0 = (const float*)d_in[4];
  const float* Wih1 = (const float*)d_in[5];
  const float* Whh1 = (const float*)d_in[6];
  const float* bih1 = (const float*)d_in[7];
  const float* bhh1 = (const float*)d_in[8];
  const float* Wout = (const float*)d_in[9];
  const float* bout = (const float*)d_in[10];

  char* ws = (char*)d_ws;
  // ws layout (bytes):
  //   [0, 16 MiB)      x as bf16, layout [b][t][256]
  //   [+, 32 MiB)      h0 sequence bf16, layout [b][t][512]
  //   then: h ping-pong L0 (256 KiB), L1 (256 KiB), flags L0/L1 (256 B each)
  __bf16* xbf   = (__bf16*)(ws);
  __bf16* h0seq = (__bf16*)(ws + 16777216);
  __bf16* hb0   = (__bf16*)(ws + 50331648);
  __bf16* hb1   = (__bf16*)(ws + 50593792);
  int*    fl0   = (int*)(ws + 50855936);
  int*    fl1   = (int*)(ws + 50856192);

  // zero h ping-pong buffers + flags (ws is poisoned before every launch)
  hipMemsetAsync(ws + 50331648, 0, 524800, stream);

  // x fp32 -> bf16 (8,388,608 elems, 8/thread)
  cvt_bf16<<<4096, 256, 0, stream>>>(x, xbf, 1048576);

  // layer 0: xsrc = xbf [b][t][256]
  gru_scan<<<64, 256, 0, stream>>>(xbf, T_STEPS * 256, 256, 256,
                                   Wih0, Whh0, bih0, bhh0, hb0, h0seq, fl0);
  // layer 1: xsrc = h0seq [b][t][512]
  gru_scan<<<64, 256, 0, stream>>>(h0seq, T_STEPS * HID, HID, HID,
                                   Wih1, Whh1, bih1, bhh1, hb1, nullptr, fl1);

  // final h1 is in ping-pong slot 0 (T even)
  outproj<<<128, 64, 0, stream>>>(hb1, Wout, bout, (float*)d_out);
}

// Round 2
// 5081.877 us; speedup vs baseline: 1.7884x; 1.7884x over previous
//
#include <hip/hip_runtime.h>
#include <hip/hip_bf16.h>
#include <stdint.h>

typedef __attribute__((ext_vector_type(8))) __bf16 bf16x8;
typedef __attribute__((ext_vector_type(4))) float  floatx4;

#define T_STEPS 256
#define BATCH   128
#define HID     512

__device__ __forceinline__ float sigmoidf_(float x) { return 1.f / (1.f + __expf(-x)); }
__device__ __forceinline__ float tanhf_(float y) {
  float e = __expf(-2.f * fabsf(y));
  return copysignf((1.f - e) / (1.f + e), y);
}

// fp32 -> bf16 elementwise (x conversion), 8 elems/thread
__global__ __launch_bounds__(256) void cvt_bf16(const float* __restrict__ in,
                                                __bf16* __restrict__ out, int n8) {
  int i = blockIdx.x * 256 + threadIdx.x;
  if (i >= n8) return;
  const floatx4* p = (const floatx4*)(in + (size_t)i * 8);
  floatx4 a = p[0], b = p[1];
  bf16x8 o;
  o[0] = (__bf16)a[0]; o[1] = (__bf16)a[1]; o[2] = (__bf16)a[2]; o[3] = (__bf16)a[3];
  o[4] = (__bf16)b[0]; o[5] = (__bf16)b[1]; o[6] = (__bf16)b[2]; o[7] = (__bf16)b[3];
  *(bf16x8*)(out + (size_t)i * 8) = o;
}

// Persistent GRU layer scan.
// Grid = 128 blocks = 2 batch-groups (64 rows each) x 64 hidden-groups (8 cols each).
// W slice (gates r,z,n for the block's 8 cols) lives in LDS in MFMA-frag order;
// the h-part fragments are additionally hoisted into registers (WH).
// Cross-block h exchange per step:
//   producers: packed 4B relaxed AGENT atomic stores (write-through to L3, no
//              dirty L2) -> vmcnt drain via __syncthreads -> relaxed flag store.
//   consumers: relaxed flag poll (no per-spin invalidate) -> one acquire fence
//              (buffer_inv) -> normal cached b128 h loads (L2-shared refill).
// Sync latency hidden by computing next step's x-phase between post and poll.
__global__ __launch_bounds__(256) void gru_scan(
    const __bf16* __restrict__ xsrc, int sb, int st, int Kin,
    const float* __restrict__ Wih, const float* __restrict__ Whh,
    const float* __restrict__ bih, const float* __restrict__ bhh,
    __bf16* __restrict__ hbuf,   // ping-pong [2][128][512], zero-initialized
    __bf16* __restrict__ hseq,   // [128][256][512] or nullptr
    int* flags)                  // [128] = [2 bg][64 g], zero-initialized
{
  const int tid = threadIdx.x;
  const int g   = blockIdx.x & 63;     // hidden group: cols [8g, 8g+8)
  const int bg  = blockIdx.x >> 6;     // batch group: rows [64bg, 64bg+64)
  const int w   = tid >> 6;            // wave 0..3, one 16-row m-tile each
  const int l   = tid & 63;
  const int c   = l & 15;
  const int q   = l >> 4;
  const int KTx = Kin >> 5;            // x-phase k-tiles (8 or 16)
  const int KT  = KTx + 16;            // + h-phase k-tiles
  const int rowbase = bg * 64 + w * 16;
  const int jj  = g * 8 + c;           // owned hidden col (lanes c<8)

  __shared__ __bf16 ldsW[2 * 32 * 64 * 8];   // 64 KiB max (KT<=32)

  // ---- stage W slice (fp32 -> bf16) into frag-order LDS
  // tile0 cols: [r0..7 | z0..7], tile1 cols: [n0..7 | zeros]
  for (int cid = tid; cid < 2 * KT * 64; cid += 256) {
    int nt = cid / (KT * 64);
    int r1 = cid - nt * (KT * 64);
    int kt = r1 >> 6;
    int ll = r1 & 63;
    int cc = ll & 15, qq = ll >> 4;
    int k  = kt * 32 + qq * 8;
    int grow;
    if (nt == 0) grow = (cc < 8) ? (g * 8 + cc) : (512 + g * 8 + (cc - 8));
    else         grow = (cc < 8) ? (1024 + g * 8 + cc) : -1;
    bf16x8 v;
    if (grow >= 0) {
      const float* src = (k < Kin) ? (Wih + (size_t)grow * Kin + k)
                                   : (Whh + (size_t)grow * HID + (k - Kin));
      #pragma unroll
      for (int j = 0; j < 8; ++j) v[j] = (__bf16)src[j];
    } else {
      #pragma unroll
      for (int j = 0; j < 8; ++j) v[j] = (__bf16)0.f;
    }
    *(bf16x8*)&ldsW[((size_t)(nt * KT + kt) * 64 + ll) * 8] = v;
  }
  __syncthreads();

  // ---- hoist the h-part W fragments into registers (constant over steps)
  bf16x8 WH[16][2];
  #pragma unroll
  for (int kt = 0; kt < 16; ++kt) {
    WH[kt][0] = *(const bf16x8*)&ldsW[((size_t)(0 * KT + KTx + kt) * 64 + l) * 8];
    WH[kt][1] = *(const bf16x8*)&ldsW[((size_t)(1 * KT + KTx + kt) * 64 + l) * 8];
  }

  // ---- per-lane biases (constant over steps)
  float bias0, bias_nx, bias_nh;
  if (c < 8) {
    bias0   = bih[jj] + bhh[jj];          // r-gate
    bias_nx = bih[1024 + jj];
    bias_nh = bhh[1024 + jj];
  } else {
    int j2 = g * 8 + (c - 8);
    bias0   = bih[512 + j2] + bhh[512 + j2];  // z-gate (consumed via shfl)
    bias_nx = 0.f; bias_nh = 0.f;
  }

  floatx4 accA[2], accB[2];
  const floatx4 zero4 = {0.f, 0.f, 0.f, 0.f};
  float hprev[4] = {0.f, 0.f, 0.f, 0.f};   // own h (lanes c<8), t=0 state

  const __bf16* xrow = xsrc + (size_t)(rowbase + c) * sb;

  auto phaseX = [&](int t) {
    accA[0] = zero4; accA[1] = zero4;
    const __bf16* xp = xrow + (size_t)t * st + q * 8;
    for (int kt = 0; kt < KTx; ++kt) {
      bf16x8 b0 = *(const bf16x8*)&ldsW[((size_t)(0 * KT + kt) * 64 + l) * 8];
      bf16x8 b1 = *(const bf16x8*)&ldsW[((size_t)(1 * KT + kt) * 64 + l) * 8];
      bf16x8 a = *(const bf16x8*)(xp + kt * 32);
      accA[0] = __builtin_amdgcn_mfma_f32_16x16x32_bf16(a, b0, accA[0], 0, 0, 0);
      accA[1] = __builtin_amdgcn_mfma_f32_16x16x32_bf16(a, b1, accA[1], 0, 0, 0);
    }
  };

  phaseX(0);

  const int* flp = flags + bg * 64;   // 64 producer flags for this batch group

  for (int t = 0; t < T_STEPS; ++t) {
    const __bf16* hR = hbuf + (size_t)(t & 1) * BATCH * HID;
    __bf16*       hW = hbuf + (size_t)((t + 1) & 1) * BATCH * HID;

    // ---- phase H: accB = h_{t-1} @ Whh_slice^T  (cached b128 loads)
    accB[0] = zero4; accB[1] = zero4;
    {
      const __bf16* hA = hR + (size_t)(rowbase + c) * HID + q * 8;
      #pragma unroll
      for (int kt = 0; kt < 16; ++kt) {
        bf16x8 a = *(const bf16x8*)(hA + kt * 32);
        accB[0] = __builtin_amdgcn_mfma_f32_16x16x32_bf16(a, WH[kt][0], accB[0], 0, 0, 0);
        accB[1] = __builtin_amdgcn_mfma_f32_16x16x32_bf16(a, WH[kt][1], accB[1], 0, 0, 0);
      }
    }

    // ---- epilogue: gates + h update; packed-pair agent stores (write-through)
    #pragma unroll
    for (int rg = 0; rg < 4; ++rg) {
      float pre0 = accA[0][rg] + accB[0][rg] + bias0;
      float zs = __shfl(pre0, (l & 48) | ((c + 8) & 15), 64);  // z from lane c+8
      float r  = sigmoidf_(pre0);
      float z  = sigmoidf_(zs);
      float nn = tanhf_(accA[1][rg] + bias_nx + r * (accB[1][rg] + bias_nh));
      float hnew = (1.f - z) * nn + z * hprev[rg];
      hprev[rg] = hnew;
      unsigned short us = __builtin_bit_cast(unsigned short, (__bf16)hnew);
      int po = __shfl_xor((int)us, 1, 64);                     // partner col's bits
      if (c < 8 && (c & 1) == 0) {
        uint32_t v = (uint32_t)us | ((uint32_t)po << 16);
        int row = rowbase + q * 4 + rg;
        __hip_atomic_store((uint32_t*)(hW + (size_t)row * HID + jj), v,
                           __ATOMIC_RELAXED, __HIP_MEMORY_SCOPE_AGENT);
        if (hseq)
          __hip_atomic_store((uint32_t*)(hseq + ((size_t)row * T_STEPS + t) * HID + jj), v,
                             __ATOMIC_RELAXED, __HIP_MEMORY_SCOPE_AGENT);
      }
    }

    if (t + 1 < T_STEPS) {
      // drain our agent stores (ack at L3), then post flag (relaxed: stores are
      // already at the coherence point, barrier provides the vmcnt(0) drain)
      asm volatile("s_waitcnt vmcnt(0)" ::: "memory");
      __syncthreads();
      if (tid == 0)
        __hip_atomic_store(&flags[bg * 64 + g], t + 1,
                           __ATOMIC_RELAXED, __HIP_MEMORY_SCOPE_AGENT);

      phaseX(t + 1);            // no h dependency -> hides barrier latency

      const int target = t + 1;
      while (1) {
        int v = __hip_atomic_load(&flp[l], __ATOMIC_RELAXED, __HIP_MEMORY_SCOPE_AGENT);
        if (__all(v >= target)) break;
      }
      // one acquire per step: invalidate L1/L2 so cached h loads see fresh data
      __builtin_amdgcn_fence(__ATOMIC_ACQUIRE, "agent");
    }
  }
}

// yhat[b][o] = h1_last[b][:] . Wout[o][:] + bout[o]
__global__ __launch_bounds__(64) void outproj(const __bf16* __restrict__ h1,
                                              const float* __restrict__ Wout,
                                              const float* __restrict__ bout,
                                              float* __restrict__ out) {
  int b = blockIdx.x, o = threadIdx.x;
  const __bf16* hr = h1 + (size_t)b * HID;
  const float*  wr = Wout + (size_t)o * HID;
  float acc = bout[o];
  for (int k = 0; k < HID; k += 8) {
    bf16x8 h8 = *(const bf16x8*)(hr + k);
    #pragma unroll
    for (int j = 0; j < 8; ++j) acc += (float)h8[j] * wr[k + j];
  }
  out[b * 64 + o] = acc;
}

extern "C" void kernel_launch(void* const* d_in, const int* in_sizes, int n_in,
                              void* d_out, int out_size, void* d_ws, size_t ws_size,
                              hipStream_t stream) {
  const float* x    = (const float*)d_in[0];
  const float* Wih0 = (const float*)d_in[1];
  const float* Whh0 = (const float*)d_in[2];
  const float* bih0 = (const float*)d_in[3];
  const float* bhh0 = (const float*)d_in[4];
  const float* Wih1 = (const float*)d_in[5];
  const float* Whh1 = (const float*)d_in[6];
  const float* bih1 = (const float*)d_in[7];
  const float* bhh1 = (const float*)d_in[8];
  const float* Wout = (const float*)d_in[9];
  const float* bout = (const float*)d_in[10];

  char* ws = (char*)d_ws;
  // ws layout (bytes):
  //   [0, 16 MiB)      x as bf16, layout [b][t][256]
  //   [+, 32 MiB)      h0 sequence bf16, layout [b][t][512]
  //   then: h ping-pong L0 (256 KiB), L1 (256 KiB), flags L0/L1 (512 B each)
  __bf16* xbf   = (__bf16*)(ws);
  __bf16* h0seq = (__bf16*)(ws + 16777216);
  __bf16* hb0   = (__bf16*)(ws + 50331648);
  __bf16* hb1   = (__bf16*)(ws + 50593792);
  int*    fl0   = (int*)(ws + 50855936);
  int*    fl1   = (int*)(ws + 50856448);

  // zero h ping-pong buffers + flags (ws is poisoned before every launch)
  hipMemsetAsync(ws + 50331648, 0, 525312, stream);

  // x fp32 -> bf16 (8,388,608 elems, 8/thread)
  cvt_bf16<<<4096, 256, 0, stream>>>(x, xbf, 1048576);

  // layer 0: xsrc = xbf [b][t][256]
  gru_scan<<<128, 256, 0, stream>>>(xbf, T_STEPS * 256, 256, 256,
                                    Wih0, Whh0, bih0, bhh0, hb0, h0seq, fl0);
  // layer 1: xsrc = h0seq [b][t][512]
  gru_scan<<<128, 256, 0, stream>>>(h0seq, T_STEPS * HID, HID, HID,
                                    Wih1, Whh1, bih1, bhh1, hb1, nullptr, fl1);

  // final h1 is in ping-pong slot 0 (T even)
  outproj<<<128, 64, 0, stream>>>(hb1, Wout, bout, (float*)d_out);
}

// Round 3
// 4085.579 us; speedup vs baseline: 2.2246x; 1.2439x over previous
//
#include <hip/hip_runtime.h>
#include <hip/hip_bf16.h>
#include <stdint.h>

typedef __attribute__((ext_vector_type(8))) __bf16 bf16x8;
typedef __attribute__((ext_vector_type(4))) float  floatx4;
typedef __attribute__((ext_vector_type(2))) unsigned long long u64x2;

#define T_STEPS 256
#define BATCH   128
#define HID     512

__device__ __forceinline__ float sigmoidf_(float x) { return 1.f / (1.f + __expf(-x)); }
__device__ __forceinline__ float tanhf_(float y) {
  float e = __expf(-2.f * fabsf(y));
  return copysignf((1.f - e) / (1.f + e), y);
}

// fp32 -> bf16 elementwise (x conversion), 8 elems/thread
__global__ __launch_bounds__(256) void cvt_bf16(const float* __restrict__ in,
                                                __bf16* __restrict__ out, int n8) {
  int i = blockIdx.x * 256 + threadIdx.x;
  if (i >= n8) return;
  const floatx4* p = (const floatx4*)(in + (size_t)i * 8);
  floatx4 a = p[0], b = p[1];
  bf16x8 o;
  o[0] = (__bf16)a[0]; o[1] = (__bf16)a[1]; o[2] = (__bf16)a[2]; o[3] = (__bf16)a[3];
  o[4] = (__bf16)b[0]; o[5] = (__bf16)b[1]; o[6] = (__bf16)b[2]; o[7] = (__bf16)b[3];
  *(bf16x8*)(out + (size_t)i * 8) = o;
}

// Persistent GRU layer scan.
// Grid = 128 blocks = 2 batch-groups (64 rows each) x 64 hidden-groups (8 cols each).
// Per-step protocol (NO cache invalidates anywhere):
//   producer: packed 4B relaxed AGENT atomic h stores (sc0+sc1, write-through to
//             coherence point) -> s_waitcnt vmcnt(0) -> __syncthreads ->
//             relaxed flag store.
//   consumer: relaxed flag poll -> relaxed AGENT 8B atomic h loads (cache-
//             bypassing, read coherence point directly). x/W stay warm in L2.
// Sync latency hidden by computing next step's x-phase between post and poll.
__global__ __launch_bounds__(256) void gru_scan(
    const __bf16* __restrict__ xsrc, int sb, int st, int Kin,
    const float* __restrict__ Wih, const float* __restrict__ Whh,
    const float* __restrict__ bih, const float* __restrict__ bhh,
    __bf16* __restrict__ hbuf,   // ping-pong [2][128][512], zero-initialized
    __bf16* __restrict__ hseq,   // [128][256][512] or nullptr
    int* flags)                  // [128] = [2 bg][64 g], zero-initialized
{
  const int tid = threadIdx.x;
  const int g   = blockIdx.x & 63;     // hidden group: cols [8g, 8g+8)
  const int bg  = blockIdx.x >> 6;     // batch group: rows [64bg, 64bg+64)
  const int w   = tid >> 6;            // wave 0..3, one 16-row m-tile each
  const int l   = tid & 63;
  const int c   = l & 15;
  const int q   = l >> 4;
  const int KTx = Kin >> 5;            // x-phase k-tiles (8 or 16)
  const int KT  = KTx + 16;            // + h-phase k-tiles
  const int rowbase = bg * 64 + w * 16;
  const int jj  = g * 8 + c;           // owned hidden col (lanes c<8)

  __shared__ __bf16 ldsW[2 * 32 * 64 * 8];   // 64 KiB max (KT<=32)

  // ---- stage W slice (fp32 -> bf16) into frag-order LDS
  // tile0 cols: [r0..7 | z0..7], tile1 cols: [n0..7 | zeros]
  for (int cid = tid; cid < 2 * KT * 64; cid += 256) {
    int nt = cid / (KT * 64);
    int r1 = cid - nt * (KT * 64);
    int kt = r1 >> 6;
    int ll = r1 & 63;
    int cc = ll & 15, qq = ll >> 4;
    int k  = kt * 32 + qq * 8;
    int grow;
    if (nt == 0) grow = (cc < 8) ? (g * 8 + cc) : (512 + g * 8 + (cc - 8));
    else         grow = (cc < 8) ? (1024 + g * 8 + cc) : -1;
    bf16x8 v;
    if (grow >= 0) {
      const float* src = (k < Kin) ? (Wih + (size_t)grow * Kin + k)
                                   : (Whh + (size_t)grow * HID + (k - Kin));
      #pragma unroll
      for (int j = 0; j < 8; ++j) v[j] = (__bf16)src[j];
    } else {
      #pragma unroll
      for (int j = 0; j < 8; ++j) v[j] = (__bf16)0.f;
    }
    *(bf16x8*)&ldsW[((size_t)(nt * KT + kt) * 64 + ll) * 8] = v;
  }
  __syncthreads();

  // ---- hoist the h-part W fragments into registers (constant over steps)
  bf16x8 WH[16][2];
  #pragma unroll
  for (int kt = 0; kt < 16; ++kt) {
    WH[kt][0] = *(const bf16x8*)&ldsW[((size_t)(0 * KT + KTx + kt) * 64 + l) * 8];
    WH[kt][1] = *(const bf16x8*)&ldsW[((size_t)(1 * KT + KTx + kt) * 64 + l) * 8];
  }

  // ---- per-lane biases (constant over steps)
  float bias0, bias_nx, bias_nh;
  if (c < 8) {
    bias0   = bih[jj] + bhh[jj];          // r-gate
    bias_nx = bih[1024 + jj];
    bias_nh = bhh[1024 + jj];
  } else {
    int j2 = g * 8 + (c - 8);
    bias0   = bih[512 + j2] + bhh[512 + j2];  // z-gate (consumed via shfl)
    bias_nx = 0.f; bias_nh = 0.f;
  }

  floatx4 accA[2], accB[2];
  const floatx4 zero4 = {0.f, 0.f, 0.f, 0.f};
  float hprev[4] = {0.f, 0.f, 0.f, 0.f};   // own h (lanes c<8), t=0 state

  const __bf16* xrow = xsrc + (size_t)(rowbase + c) * sb;

  auto phaseX = [&](int t) {
    accA[0] = zero4; accA[1] = zero4;
    const __bf16* xp = xrow + (size_t)t * st + q * 8;
    for (int kt = 0; kt < KTx; ++kt) {
      bf16x8 b0 = *(const bf16x8*)&ldsW[((size_t)(0 * KT + kt) * 64 + l) * 8];
      bf16x8 b1 = *(const bf16x8*)&ldsW[((size_t)(1 * KT + kt) * 64 + l) * 8];
      bf16x8 a = *(const bf16x8*)(xp + kt * 32);
      accA[0] = __builtin_amdgcn_mfma_f32_16x16x32_bf16(a, b0, accA[0], 0, 0, 0);
      accA[1] = __builtin_amdgcn_mfma_f32_16x16x32_bf16(a, b1, accA[1], 0, 0, 0);
    }
  };

  phaseX(0);

  const int* flp = flags + bg * 64;   // 64 producer flags for this batch group

  for (int t = 0; t < T_STEPS; ++t) {
    const __bf16* hR = hbuf + (size_t)(t & 1) * BATCH * HID;
    __bf16*       hW = hbuf + (size_t)((t + 1) & 1) * BATCH * HID;

    // ---- phase H: accB = h_{t-1} @ Whh_slice^T
    // cache-bypassing 8B atomic loads, all issued before the MFMAs (one
    // overlapped coherence-point round trip)
    accB[0] = zero4; accB[1] = zero4;
    {
      const unsigned long long* hA =
          (const unsigned long long*)hR + (size_t)(rowbase + c) * 128 + q * 2;
      bf16x8 hfrag[16];
      #pragma unroll
      for (int kt = 0; kt < 16; ++kt) {
        unsigned long long lo = __hip_atomic_load(hA + kt * 8,
                                  __ATOMIC_RELAXED, __HIP_MEMORY_SCOPE_AGENT);
        unsigned long long hi = __hip_atomic_load(hA + kt * 8 + 1,
                                  __ATOMIC_RELAXED, __HIP_MEMORY_SCOPE_AGENT);
        u64x2 p; p[0] = lo; p[1] = hi;
        hfrag[kt] = __builtin_bit_cast(bf16x8, p);
      }
      #pragma unroll
      for (int kt = 0; kt < 16; ++kt) {
        accB[0] = __builtin_amdgcn_mfma_f32_16x16x32_bf16(hfrag[kt], WH[kt][0], accB[0], 0, 0, 0);
        accB[1] = __builtin_amdgcn_mfma_f32_16x16x32_bf16(hfrag[kt], WH[kt][1], accB[1], 0, 0, 0);
      }
    }

    // ---- epilogue: gates + h update; packed-pair agent stores (write-through)
    #pragma unroll
    for (int rg = 0; rg < 4; ++rg) {
      float pre0 = accA[0][rg] + accB[0][rg] + bias0;
      float zs = __shfl(pre0, (l & 48) | ((c + 8) & 15), 64);  // z from lane c+8
      float r  = sigmoidf_(pre0);
      float z  = sigmoidf_(zs);
      float nn = tanhf_(accA[1][rg] + bias_nx + r * (accB[1][rg] + bias_nh));
      float hnew = (1.f - z) * nn + z * hprev[rg];
      hprev[rg] = hnew;
      unsigned short us = __builtin_bit_cast(unsigned short, (__bf16)hnew);
      int po = __shfl_xor((int)us, 1, 64);                     // partner col's bits
      if (c < 8 && (c & 1) == 0) {
        uint32_t v = (uint32_t)us | ((uint32_t)po << 16);
        int row = rowbase + q * 4 + rg;
        __hip_atomic_store((uint32_t*)(hW + (size_t)row * HID + jj), v,
                           __ATOMIC_RELAXED, __HIP_MEMORY_SCOPE_AGENT);
        if (hseq)   // consumed only by the NEXT kernel: plain cached store
          *(uint32_t*)(hseq + ((size_t)row * T_STEPS + t) * HID + jj) = v;
      }
    }

    if (t + 1 < T_STEPS) {
      // drain our h stores to the coherence point, then post flag (relaxed:
      // the data is already globally visible, no release fence needed)
      asm volatile("s_waitcnt vmcnt(0)" ::: "memory");
      __syncthreads();
      if (tid == 0)
        __hip_atomic_store(&flags[bg * 64 + g], t + 1,
                           __ATOMIC_RELAXED, __HIP_MEMORY_SCOPE_AGENT);

      phaseX(t + 1);            // no h dependency -> hides flag flight

      const int target = t + 1;
      while (1) {
        int v = __hip_atomic_load(&flp[l], __ATOMIC_RELAXED, __HIP_MEMORY_SCOPE_AGENT);
        if (__all(v >= target)) break;
      }
      asm volatile("" ::: "memory");  // compiler barrier: keep h loads below poll
    }
  }
}

// yhat[b][o] = h1_last[b][:] . Wout[o][:] + bout[o]
__global__ __launch_bounds__(64) void outproj(const __bf16* __restrict__ h1,
                                              const float* __restrict__ Wout,
                                              const float* __restrict__ bout,
                                              float* __restrict__ out) {
  int b = blockIdx.x, o = threadIdx.x;
  const __bf16* hr = h1 + (size_t)b * HID;
  const float*  wr = Wout + (size_t)o * HID;
  float acc = bout[o];
  for (int k = 0; k < HID; k += 8) {
    bf16x8 h8 = *(const bf16x8*)(hr + k);
    #pragma unroll
    for (int j = 0; j < 8; ++j) acc += (float)h8[j] * wr[k + j];
  }
  out[b * 64 + o] = acc;
}

extern "C" void kernel_launch(void* const* d_in, const int* in_sizes, int n_in,
                              void* d_out, int out_size, void* d_ws, size_t ws_size,
                              hipStream_t stream) {
  const float* x    = (const float*)d_in[0];
  const float* Wih0 = (const float*)d_in[1];
  const float* Whh0 = (const float*)d_in[2];
  const float* bih0 = (const float*)d_in[3];
  const float* bhh0 = (const float*)d_in[4];
  const float* Wih1 = (const float*)d_in[5];
  const float* Whh1 = (const float*)d_in[6];
  const float* bih1 = (const float*)d_in[7];
  const float* bhh1 = (const float*)d_in[8];
  const float* Wout = (const float*)d_in[9];
  const float* bout = (const float*)d_in[10];

  char* ws = (char*)d_ws;
  // ws layout (bytes):
  //   [0, 16 MiB)      x as bf16, layout [b][t][256]
  //   [+, 32 MiB)      h0 sequence bf16, layout [b][t][512]
  //   then: h ping-pong L0 (256 KiB), L1 (256 KiB), flags L0/L1 (512 B each)
  __bf16* xbf   = (__bf16*)(ws);
  __bf16* h0seq = (__bf16*)(ws + 16777216);
  __bf16* hb0   = (__bf16*)(ws + 50331648);
  __bf16* hb1   = (__bf16*)(ws + 50593792);
  int*    fl0   = (int*)(ws + 50855936);
  int*    fl1   = (int*)(ws + 50856448);

  // zero h ping-pong buffers + flags (ws is poisoned before every launch)
  hipMemsetAsync(ws + 50331648, 0, 525312, stream);

  // x fp32 -> bf16 (8,388,608 elems, 8/thread)
  cvt_bf16<<<4096, 256, 0, stream>>>(x, xbf, 1048576);

  // layer 0: xsrc = xbf [b][t][256]
  gru_scan<<<128, 256, 0, stream>>>(xbf, T_STEPS * 256, 256, 256,
                                    Wih0, Whh0, bih0, bhh0, hb0, h0seq, fl0);
  // layer 1: xsrc = h0seq [b][t][512]
  gru_scan<<<128, 256, 0, stream>>>(h0seq, T_STEPS * HID, HID, HID,
                                    Wih1, Whh1, bih1, bhh1, hb1, nullptr, fl1);

  // final h1 is in ping-pong slot 0 (T even)
  outproj<<<128, 64, 0, stream>>>(hb1, Wout, bout, (float*)d_out);
}

// Round 4
// 3503.323 us; speedup vs baseline: 2.5943x; 1.1662x over previous
//
#include <hip/hip_runtime.h>
#include <hip/hip_bf16.h>
#include <stdint.h>

typedef __attribute__((ext_vector_type(8))) __bf16 bf16x8;
typedef __attribute__((ext_vector_type(4))) float  floatx4;

#define T_STEPS 256
#define BATCH   128
#define HID     512

__device__ __forceinline__ float sigmoidf_(float x) { return 1.f / (1.f + __expf(-x)); }
__device__ __forceinline__ float tanhf_(float y) {
  float e = __expf(-2.f * fabsf(y));
  return copysignf((1.f - e) / (1.f + e), y);
}

// fp32 [b][t][256] -> bf16 time-major [t][b][256], 8 elems/thread
__global__ __launch_bounds__(256) void cvt_bf16_tmajor(const float* __restrict__ in,
                                                       __bf16* __restrict__ out) {
  int id = blockIdx.x * 256 + threadIdx.x;     // [0, 1048576)
  int i8 = id & 31;
  int bt = id >> 5;
  int t  = bt & 255;
  int b  = bt >> 8;
  const floatx4* p = (const floatx4*)(in + ((size_t)(b * 256 + t) * 256 + i8 * 8));
  floatx4 a = p[0], v = p[1];
  bf16x8 o;
  o[0] = (__bf16)a[0]; o[1] = (__bf16)a[1]; o[2] = (__bf16)a[2]; o[3] = (__bf16)a[3];
  o[4] = (__bf16)v[0]; o[5] = (__bf16)v[1]; o[6] = (__bf16)v[2]; o[7] = (__bf16)v[3];
  *(bf16x8*)(out + ((size_t)(t * 128 + b) * 256 + i8 * 8)) = o;
}

// Persistent GRU layer scan.
// Grid = 128 blocks = 2 batch-groups (64 rows each) x 64 hidden-groups (8 cols each).
// h exchange: FRESH time-major slab per step (slab t = h after step t, [128][512]).
// Addresses are never reused, so consumer L2s can never hold a stale copy:
//   producer: packed 4B relaxed AGENT atomic stores (write-through to coherence
//             point) -> s_waitcnt vmcnt(0) -> __syncthreads -> relaxed flag store.
//   consumer: relaxed flag poll -> PLAIN cached b128 h loads (first toucher per
//             XCD misses to L3, rest hit L2). No invalidates, no atomic loads.
// Sync latency hidden by computing next step's x-phase between post and poll.
// Slab arrays are split in two regions (lo: t<128, hi: t>=128) so layer 1 can
// overlay the dead xbf region (cross-kernel visibility via kernel-boundary
// acquire/release).
__global__ __launch_bounds__(256) void gru_scan(
    const __bf16* __restrict__ xLo, const __bf16* __restrict__ xHi, int Kin,
    const float* __restrict__ Wih, const float* __restrict__ Whh,
    const float* __restrict__ bih, const float* __restrict__ bhh,
    __bf16* __restrict__ hLo, __bf16* __restrict__ hHi,  // 128 slabs each
    int* flags)                  // [128] = [2 bg][64 g], zero-initialized
{
  const int tid = threadIdx.x;
  const int g   = blockIdx.x & 63;     // hidden group: cols [8g, 8g+8)
  const int bg  = blockIdx.x >> 6;     // batch group: rows [64bg, 64bg+64)
  const int w   = tid >> 6;            // wave 0..3, one 16-row m-tile each
  const int l   = tid & 63;
  const int c   = l & 15;
  const int q   = l >> 4;
  const int KTx = Kin >> 5;            // x-phase k-tiles (8 or 16)
  const int KT  = KTx + 16;            // + h-phase k-tiles
  const int rowbase = bg * 64 + w * 16;
  const int jj  = g * 8 + c;           // owned hidden col (lanes c<8)

  __shared__ __bf16 ldsW[2 * 32 * 64 * 8];   // 64 KiB max (KT<=32)

  auto hslab = [&](int t) -> __bf16* {
    return (t < 128 ? hLo : hHi) + (size_t)(t & 127) * (BATCH * HID);
  };
  auto xslab = [&](int t) -> const __bf16* {
    return (t < 128 ? xLo : xHi) + (size_t)(t & 127) * (size_t)(BATCH * Kin);
  };

  // ---- stage W slice (fp32 -> bf16) into frag-order LDS
  // tile0 cols: [r0..7 | z0..7], tile1 cols: [n0..7 | zeros]
  for (int cid = tid; cid < 2 * KT * 64; cid += 256) {
    int nt = cid / (KT * 64);
    int r1 = cid - nt * (KT * 64);
    int kt = r1 >> 6;
    int ll = r1 & 63;
    int cc = ll & 15, qq = ll >> 4;
    int k  = kt * 32 + qq * 8;
    int grow;
    if (nt == 0) grow = (cc < 8) ? (g * 8 + cc) : (512 + g * 8 + (cc - 8));
    else         grow = (cc < 8) ? (1024 + g * 8 + cc) : -1;
    bf16x8 v;
    if (grow >= 0) {
      const float* src = (k < Kin) ? (Wih + (size_t)grow * Kin + k)
                                   : (Whh + (size_t)grow * HID + (k - Kin));
      #pragma unroll
      for (int j = 0; j < 8; ++j) v[j] = (__bf16)src[j];
    } else {
      #pragma unroll
      for (int j = 0; j < 8; ++j) v[j] = (__bf16)0.f;
    }
    *(bf16x8*)&ldsW[((size_t)(nt * KT + kt) * 64 + ll) * 8] = v;
  }
  __syncthreads();

  // ---- hoist the h-part W fragments (compiler may keep in regs or re-read LDS)
  bf16x8 WH[16][2];
  #pragma unroll
  for (int kt = 0; kt < 16; ++kt) {
    WH[kt][0] = *(const bf16x8*)&ldsW[((size_t)(0 * KT + KTx + kt) * 64 + l) * 8];
    WH[kt][1] = *(const bf16x8*)&ldsW[((size_t)(1 * KT + KTx + kt) * 64 + l) * 8];
  }

  // ---- per-lane biases (constant over steps)
  float bias0, bias_nx, bias_nh;
  if (c < 8) {
    bias0   = bih[jj] + bhh[jj];          // r-gate
    bias_nx = bih[1024 + jj];
    bias_nh = bhh[1024 + jj];
  } else {
    int j2 = g * 8 + (c - 8);
    bias0   = bih[512 + j2] + bhh[512 + j2];  // z-gate (consumed via shfl)
    bias_nx = 0.f; bias_nh = 0.f;
  }

  floatx4 accA[2], accB[2];
  const floatx4 zero4 = {0.f, 0.f, 0.f, 0.f};
  float hprev[4] = {0.f, 0.f, 0.f, 0.f};   // own h (lanes c<8), t=0 state

  auto phaseX = [&](int t) {
    accA[0] = zero4; accA[1] = zero4;
    const __bf16* xp = xslab(t) + (size_t)(rowbase + c) * Kin + q * 8;
    for (int kt = 0; kt < KTx; ++kt) {
      bf16x8 b0 = *(const bf16x8*)&ldsW[((size_t)(0 * KT + kt) * 64 + l) * 8];
      bf16x8 b1 = *(const bf16x8*)&ldsW[((size_t)(1 * KT + kt) * 64 + l) * 8];
      bf16x8 a = *(const bf16x8*)(xp + kt * 32);
      accA[0] = __builtin_amdgcn_mfma_f32_16x16x32_bf16(a, b0, accA[0], 0, 0, 0);
      accA[1] = __builtin_amdgcn_mfma_f32_16x16x32_bf16(a, b1, accA[1], 0, 0, 0);
    }
  };

  phaseX(0);

  const int* flp = flags + bg * 64;   // 64 producer flags for this batch group

  for (int t = 0; t < T_STEPS; ++t) {
    // ---- phase H: accB = h_{t-1} @ Whh_slice^T  (plain cached b128 loads,
    //      slab t-1 is fresh-addressed so no staleness is possible)
    accB[0] = zero4; accB[1] = zero4;
    if (t > 0) {
      const __bf16* hA = hslab(t - 1) + (size_t)(rowbase + c) * HID + q * 8;
      bf16x8 hfrag[16];
      #pragma unroll
      for (int kt = 0; kt < 16; ++kt)
        hfrag[kt] = *(const bf16x8*)(hA + kt * 32);
      #pragma unroll
      for (int kt = 0; kt < 16; ++kt) {
        accB[0] = __builtin_amdgcn_mfma_f32_16x16x32_bf16(hfrag[kt], WH[kt][0], accB[0], 0, 0, 0);
        accB[1] = __builtin_amdgcn_mfma_f32_16x16x32_bf16(hfrag[kt], WH[kt][1], accB[1], 0, 0, 0);
      }
    }

    // ---- epilogue: gates + h update; packed-pair agent stores (write-through)
    __bf16* hs = hslab(t);
    #pragma unroll
    for (int rg = 0; rg < 4; ++rg) {
      float pre0 = accA[0][rg] + accB[0][rg] + bias0;
      float zs = __shfl(pre0, (l & 48) | ((c + 8) & 15), 64);  // z from lane c+8
      float r  = sigmoidf_(pre0);
      float z  = sigmoidf_(zs);
      float nn = tanhf_(accA[1][rg] + bias_nx + r * (accB[1][rg] + bias_nh));
      float hnew = (1.f - z) * nn + z * hprev[rg];
      hprev[rg] = hnew;
      unsigned short us = __builtin_bit_cast(unsigned short, (__bf16)hnew);
      int po = __shfl_xor((int)us, 1, 64);                     // partner col's bits
      if (c < 8 && (c & 1) == 0) {
        uint32_t v = (uint32_t)us | ((uint32_t)po << 16);
        int row = rowbase + q * 4 + rg;
        __hip_atomic_store((uint32_t*)(hs + (size_t)row * HID + jj), v,
                           __ATOMIC_RELAXED, __HIP_MEMORY_SCOPE_AGENT);
      }
    }

    if (t + 1 < T_STEPS) {
      // drain our h stores to the coherence point, then post flag (relaxed:
      // the data is already globally visible, no release fence needed)
      asm volatile("s_waitcnt vmcnt(0)" ::: "memory");
      __syncthreads();
      if (tid == 0)
        __hip_atomic_store(&flags[bg * 64 + g], t + 1,
                           __ATOMIC_RELAXED, __HIP_MEMORY_SCOPE_AGENT);

      phaseX(t + 1);            // no h dependency -> hides flag flight

      const int target = t + 1;
      while (1) {
        int v = __hip_atomic_load(&flp[l], __ATOMIC_RELAXED, __HIP_MEMORY_SCOPE_AGENT);
        if (__all(v >= target)) break;
      }
      asm volatile("" ::: "memory");  // compiler barrier: keep h loads below poll
    }
  }
}

// yhat[b][o] = h1_last[b][:] . Wout[o][:] + bout[o]
__global__ __launch_bounds__(64) void outproj(const __bf16* __restrict__ h1,
                                              const float* __restrict__ Wout,
                                              const float* __restrict__ bout,
                                              float* __restrict__ out) {
  int b = blockIdx.x, o = threadIdx.x;
  const __bf16* hr = h1 + (size_t)b * HID;
  const float*  wr = Wout + (size_t)o * HID;
  float acc = bout[o];
  for (int k = 0; k < HID; k += 8) {
    bf16x8 h8 = *(const bf16x8*)(hr + k);
    #pragma unroll
    for (int j = 0; j < 8; ++j) acc += (float)h8[j] * wr[k + j];
  }
  out[b * 64 + o] = acc;
}

extern "C" void kernel_launch(void* const* d_in, const int* in_sizes, int n_in,
                              void* d_out, int out_size, void* d_ws, size_t ws_size,
                              hipStream_t stream) {
  const float* x    = (const float*)d_in[0];
  const float* Wih0 = (const float*)d_in[1];
  const float* Whh0 = (const float*)d_in[2];
  const float* bih0 = (const float*)d_in[3];
  const float* bhh0 = (const float*)d_in[4];
  const float* Wih1 = (const float*)d_in[5];
  const float* Whh1 = (const float*)d_in[6];
  const float* bih1 = (const float*)d_in[7];
  const float* bhh1 = (const float*)d_in[8];
  const float* Wout = (const float*)d_in[9];
  const float* bout = (const float*)d_in[10];

  char* ws = (char*)d_ws;
  // ws layout (bytes):
  //   [0, 16 MiB)       xbf: x as bf16 time-major [t][b][256]  (256 slabs x 64 KB)
  //                     ... later OVERLAID by h1seq slabs [0,128) (layer 0 done)
  //   [16 MiB, 48 MiB)  h0seq: 256 slabs x 128 KB ([t][b][512])
  //   [48 MiB, 64 MiB)  h1seq slabs [128, 256)
  //   [64 MiB, +1 KiB)  flags layer0 [128], layer1 [128]
  __bf16* xbf  = (__bf16*)(ws);
  __bf16* h0lo = (__bf16*)(ws + (16u << 20));
  __bf16* h0hi = (__bf16*)(ws + (32u << 20));
  __bf16* h1lo = (__bf16*)(ws);                 // overlay on dead xbf
  __bf16* h1hi = (__bf16*)(ws + (48u << 20));
  int*    fl0  = (int*)(ws + (64u << 20));
  int*    fl1  = fl0 + 128;

  // zero the flags (ws is poisoned before every launch)
  hipMemsetAsync(fl0, 0, 1024, stream);

  // x fp32 -> bf16 time-major (1,048,576 threads x 8 elems)
  cvt_bf16_tmajor<<<4096, 256, 0, stream>>>(x, xbf);

  const __bf16* x0hi = xbf + (size_t)128 * 128 * 256;   // slab 128 of x

  // layer 0: x slabs = xbf (64 KB each), h slabs = h0seq
  gru_scan<<<128, 256, 0, stream>>>(xbf, x0hi, 256,
                                    Wih0, Whh0, bih0, bhh0, h0lo, h0hi, fl0);
  // layer 1: x slabs = h0seq (128 KB each), h slabs = h1seq (overlaid)
  gru_scan<<<128, 256, 0, stream>>>(h0lo, h0hi, HID,
                                    Wih1, Whh1, bih1, bhh1, h1lo, h1hi, fl1);

  // final h1 = slab 255 = h1hi + 127 slabs
  outproj<<<128, 64, 0, stream>>>(h1hi + (size_t)127 * BATCH * HID,
                                  Wout, bout, (float*)d_out);
}